// Round 4
// baseline (104.729 us; speedup 1.0000x reference)
//
#include <hip/hip_runtime.h>
#include <math.h>

#define BB 2
#define CC 10
#define NN 100
#define MM 50
#define HP 24
#define WP 24
#define HH 96
#define WW 96
#define HW (HH*WW)            // 9216
#define KCHUNKS 16
#define CHUNK (HW/KCHUNKS)    // 576
#define KC 64
#define NSTEPS (CHUNK/KC)     // 9
#define PAD 68                // 64 + 4 pad: b128 reads at worst 2-way bank aliasing (free)

static __device__ __forceinline__ float dot4(float4 a, float4 b) {
    return a.x*b.x + a.y*b.y + a.z*b.z + a.w*b.w;
}

// ---------------------------------------------------------------------------
// Kernel A (fused producer): blocks 0..199 do bilinear resize 24x24 -> 96x96
// (jax.image.resize: half-pixel centers, triangle kernel w/ edge renorm ==
// clamp) fused with per-pixel precompute
//   Q = 1 - 2p          (sum|p-t| = sumP + dot(Q,t)   for binary t, p in [0,1])
//   D = f1(p) - f0(p)   (sum focal = sumF0 + dot(D,t))
// and per-(b,n) reductions sumP, sumF0.
// Blocks 200..299 compute tsum[b,m] = sum(t) over HW (t binary => == sum|t|).
// ---------------------------------------------------------------------------
__global__ __launch_bounds__(256) void k_pre(
    const float* __restrict__ pm,         // (B,N,24,24)
    const float* __restrict__ tm,         // (B,M,96,96)
    float* __restrict__ Q, float* __restrict__ D,
    float* __restrict__ sumP, float* __restrict__ sumF0,
    float* __restrict__ tsum)
{
    const int tid = threadIdx.x;
    __shared__ float tile[HP*WP];
    __shared__ float red[8];

    if (blockIdx.x >= BB*NN) {
        // ---- tsum path ----
        const int bm = blockIdx.x - BB*NN;        // 0..BB*MM-1
        const float4* t4 = (const float4*)(tm + (size_t)bm * HW);
        float s = 0.f;
#pragma unroll
        for (int i = 0; i < 9; ++i) {             // 9216/4/256 = 9
            float4 v = t4[i*256 + tid];
            s += v.x + v.y + v.z + v.w;
        }
#pragma unroll
        for (int o = 32; o > 0; o >>= 1) s += __shfl_down(s, o);
        const int wid = tid >> 6, lane = tid & 63;
        if (lane == 0) red[wid] = s;
        __syncthreads();
        if (tid == 0) tsum[bm] = red[0] + red[1] + red[2] + red[3];
        return;
    }

    // ---- resize + Q/D path ----
    const int bn = blockIdx.x;                    // 0..BB*NN-1
    const float* in = pm + (size_t)bn * (HP*WP);
    for (int i = tid; i < HP*WP; i += 256) tile[i] = in[i];
    __syncthreads();

    float* q = Q + (size_t)bn * HW;
    float* d = D + (size_t)bn * HW;

    float sp = 0.f, sf = 0.f;
#pragma unroll 4
    for (int s = 0; s < HW/256; ++s) {
        const int idx = s*256 + tid;
        const int i = idx / WW;
        const int j = idx - i*WW;
        float y = (i + 0.5f)*0.25f - 0.5f;
        float x = (j + 0.5f)*0.25f - 0.5f;
        y = fminf(fmaxf(y, 0.f), 23.f);
        x = fminf(fmaxf(x, 0.f), 23.f);
        const int y0 = (int)y;
        const int x0 = (int)x;
        const float fy = y - (float)y0;
        const float fx = x - (float)x0;
        const int y1 = (y0 < HP-1) ? y0+1 : HP-1;
        const int x1 = (x0 < WP-1) ? x0+1 : WP-1;
        const float v00 = tile[y0*WP + x0], v01 = tile[y0*WP + x1];
        const float v10 = tile[y1*WP + x0], v11 = tile[y1*WP + x1];
        const float p = (1.f-fy)*((1.f-fx)*v00 + fx*v01)
                      +       fy*((1.f-fx)*v10 + fx*v11);

        const float pc  = fminf(fmaxf(p, 0.001f), 0.999f);
        const float omc = 1.f - pc;
        const float f1 = 0.25f * (-logf(pc))  * omc*omc;   // t==1 focal term
        const float f0 = 0.75f * (-logf(omc)) * pc*pc;     // t==0 focal term

        q[idx] = 1.f - 2.f*p;
        d[idx] = f1 - f0;
        sp += p;
        sf += f0;
    }

#pragma unroll
    for (int o = 32; o > 0; o >>= 1) {
        sp += __shfl_down(sp, o);
        sf += __shfl_down(sf, o);
    }
    const int wid = tid >> 6, lane = tid & 63;
    if (lane == 0) { red[wid] = sp; red[4+wid] = sf; }
    __syncthreads();
    if (tid == 0) {
        sumP[bn]  = red[0] + red[1] + red[2] + red[3];
        sumF0[bn] = red[4] + red[5] + red[6] + red[7];
    }
}

// ---------------------------------------------------------------------------
// Kernel B: the dual dot products
//   pNeg[kc,b,n,m] = dot(Q[b,n, chunk], T[b,m, chunk])
//   pF  [kc,b,n,m] = dot(D[b,n, chunk], T[b,m, chunk])
// Tiled 32n x 32m per block, 2x2 register blocking per thread, k split into
// 16 chunks of 576. grid = (16, 4*2, 2), 256 threads.
// ---------------------------------------------------------------------------
__global__ __launch_bounds__(256) void k_dots(
    const float* __restrict__ Q, const float* __restrict__ D,
    const float* __restrict__ T,
    float* __restrict__ pNeg, float* __restrict__ pF)
{
    const int kc = blockIdx.x;               // 0..15
    const int nt = blockIdx.y >> 1;          // 0..3
    const int mt = blockIdx.y & 1;           // 0..1
    const int b  = blockIdx.z;               // 0..1
    const int tid = threadIdx.x;
    const int ni = tid >> 4;                 // 0..15
    const int mi = tid & 15;                 // 0..15

    __shared__ float tS[32][PAD];
    __shared__ float qS[32][PAD];
    __shared__ float dS[32][PAD];

    const int n0 = nt*32, m0 = mt*32;
    const int k0 = kc*CHUNK;

    // loader mapping: thread -> (row = tid>>3, 8 contiguous floats at (tid&7)*8)
    const int lr  = tid >> 3;                // 0..31
    const int lcb = (tid & 7) * 8;           // 0,8,..,56

    float accN[2][2] = {{0.f,0.f},{0.f,0.f}};
    float accF[2][2] = {{0.f,0.f},{0.f,0.f}};

    for (int s = 0; s < NSTEPS; ++s) {
        const int kb = k0 + s*KC;
        // ---- stage ----
        {
            const int n = n0 + lr;
            float4 qa = {0,0,0,0}, qb = {0,0,0,0}, da = {0,0,0,0}, db = {0,0,0,0};
            if (n < NN) {
                const float* qp = Q + ((size_t)b*NN + n)*HW + kb + lcb;
                const float* dp = D + ((size_t)b*NN + n)*HW + kb + lcb;
                qa = *(const float4*)qp;     qb = *(const float4*)(qp+4);
                da = *(const float4*)dp;     db = *(const float4*)(dp+4);
            }
            *(float4*)&qS[lr][lcb]   = qa;   *(float4*)&qS[lr][lcb+4] = qb;
            *(float4*)&dS[lr][lcb]   = da;   *(float4*)&dS[lr][lcb+4] = db;

            const int m = m0 + lr;
            float4 ta = {0,0,0,0}, tb = {0,0,0,0};
            if (m < MM) {
                const float* tp = T + ((size_t)b*MM + m)*HW + kb + lcb;
                ta = *(const float4*)tp;     tb = *(const float4*)(tp+4);
            }
            *(float4*)&tS[lr][lcb]   = ta;   *(float4*)&tS[lr][lcb+4] = tb;
        }
        __syncthreads();
        // ---- compute ----
#pragma unroll
        for (int kk = 0; kk < KC; kk += 4) {
            const float4 t0 = *(const float4*)&tS[mi   ][kk];
            const float4 t1 = *(const float4*)&tS[mi+16][kk];
            const float4 q0 = *(const float4*)&qS[ni   ][kk];
            const float4 q1 = *(const float4*)&qS[ni+16][kk];
            const float4 d0 = *(const float4*)&dS[ni   ][kk];
            const float4 d1 = *(const float4*)&dS[ni+16][kk];
            accN[0][0] += dot4(q0, t0);  accN[0][1] += dot4(q0, t1);
            accN[1][0] += dot4(q1, t0);  accN[1][1] += dot4(q1, t1);
            accF[0][0] += dot4(d0, t0);  accF[0][1] += dot4(d0, t1);
            accF[1][0] += dot4(d1, t0);  accF[1][1] += dot4(d1, t1);
        }
        __syncthreads();
    }

#pragma unroll
    for (int a = 0; a < 2; ++a)
#pragma unroll
        for (int c = 0; c < 2; ++c) {
            const int n = n0 + ni + a*16;
            const int m = m0 + mi + c*16;
            if (n < NN && m < MM) {
                const size_t o = (((size_t)kc*BB + b)*NN + n)*MM + m;
                pNeg[o] = accN[a][c];
                pF[o]   = accF[a][c];
            }
        }
}

// ---------------------------------------------------------------------------
// Kernel C: finalize — combine partials + dice/focal closed forms + class +
// momentum L1 / EIoU + class>0 mask. One thread per (b,n,m).
// ---------------------------------------------------------------------------
__global__ __launch_bounds__(256) void k_final(
    const float* __restrict__ pNeg, const float* __restrict__ pF,
    const float* __restrict__ sumP, const float* __restrict__ sumF0,
    const float* __restrict__ tsum,
    const float* __restrict__ prob,      // (B,C,N)
    const float* __restrict__ pmom,      // (B,N,4)
    const int*   __restrict__ tcls,      // (B,M)
    const float* __restrict__ tmom,      // (B,M,4)
    float* __restrict__ out)             // (B,N,M)
{
    const int idx = blockIdx.x*256 + threadIdx.x;
    if (idx >= BB*NN*MM) return;
    const int m = idx % MM;
    const int n = (idx / MM) % NN;
    const int b = idx / (NN*MM);

    const float PI_F     = 3.14159265358979323846f;
    const float TWO_PI_F = 6.28318530717958647692f;

    float nd = 0.f, fd = 0.f;
#pragma unroll
    for (int kc = 0; kc < KCHUNKS; ++kc) {
        const size_t o = (((size_t)kc*BB + b)*NN + n)*MM + m;
        nd += pNeg[o];
        fd += pF[o];
    }
    const float sp  = sumP[b*NN + n];
    const float sf0 = sumF0[b*NN + n];
    const float ts  = tsum[b*MM + m];

    const float neg = sp + nd;                    // sum |p - t|
    const float pos = sp + ts;                    // sum|p| + sum|t|
    const float cost_dice  = 1.f - (pos - neg) / (pos + 0.001f);
    const float cost_focal = (sf0 + fd) * (1.f / (float)HW);

    const int tc = tcls[b*MM + m];
    const float cost_class = -prob[((size_t)b*CC + tc)*NN + n];

    // calc_bbox(pred_momentum[b,n])
    const float* pr = pmom + ((size_t)b*NN + n)*4;
    const float p0 = expf(fminf(pr[0], 10.f));                       // pt
    const float p1 = TWO_PI_F / (1.f + expf(-pr[1]));                // rap
    const float p2 = TWO_PI_F / (1.f + expf(-pr[2]));                // phi
    const float p3 = expf(fminf(pr[3], 10.f));                       // m

    const float* tg = tmom + ((size_t)b*MM + m)*4;
    const float t0 = tg[0], t1 = tg[1], t2 = tg[2], t3 = tg[3];

    // ---- momentum L1 ----
    const float te2 = (p2 - t2 > PI_F) ? TWO_PI_F : 0.f;  // added to tgt phi
    const float pe2 = (t2 - p2 > PI_F) ? TWO_PI_F : 0.f;  // added to pred phi
    const float e0 = p0 / (t0 + 0.001f);
    const float e1 = p1 / (t1 + 0.001f);
    const float e2 = (p2 + pe2) / (t2 + te2 + 0.001f);
    const float e3 = p3 / (t3 + 0.001f);
    const float cost_l1 = 0.25f * (fabsf(e0 - 1.f) + fabsf(e1 - 1.f)
                                 + fabsf(e2 - 1.f) + fabsf(e3 - 1.f));

    // ---- EIoU ----  (w1,x1,y1,h1) = pred bbox, (w2,x2,y2,h2) = target
    const float w1 = p0, x1 = p1, y1o = p2, h1 = p3;
    const float w2 = t0, x2 = t1, y2o = t2, h2 = t3;
    const float y1 = y1o + ((y2o - y1o > PI_F) ? TWO_PI_F : 0.f);
    const float y2 = y2o + ((y1o - y2o > PI_F) ? TWO_PI_F : 0.f);

    const float xr1 = x1 + w1*0.5f, xl1 = x1 - w1*0.5f;
    const float xr2 = x2 + w2*0.5f, xl2 = x2 - w2*0.5f;
    const float yr1 = y1 + h1*0.5f, yl1 = y1 - h1*0.5f;
    const float yr2 = y2 + h2*0.5f, yl2 = y2 - h2*0.5f;

    const float wi = fminf(xr1, xr2) - fmaxf(xl1, xl2);
    const float hi = fminf(yr1, yr2) - fmaxf(yl1, yl2);
    const float iou = (wi > 0.f && hi > 0.f)
        ? wi*hi / (w1*h1 + w2*h2 - wi*hi + 0.001f) : 0.f;

    const float cw = fmaxf(xr1, xr2) - fminf(xl1, xl2);
    const float ch = fmaxf(yr1, yr2) - fminf(yl1, yl2);
    const float cw2 = cw*cw, ch2 = ch*ch;
    const float rho_w = (w1 - w2)*(w1 - w2) / (cw2 + 0.001f);
    const float rho_h = (h1 - h2)*(h1 - h2) / (ch2 + 0.001f);
    const float rho_d = ((x1 - x2)*(x1 - x2) + (y1 - y2)*(y1 - y2))
                        / (cw2 + ch2 + 0.001f);
    const float cost_eiou = 1.f - iou + rho_d + rho_w + rho_h;

    const float cost = 0.25f*cost_focal + 0.75f*cost_dice + cost_class
                     + 0.8f*cost_l1 + 0.2f*cost_eiou;
    out[idx] = (tc > 0) ? cost : 100000.0f;
}

// ---------------------------------------------------------------------------
extern "C" void kernel_launch(void* const* d_in, const int* in_sizes, int n_in,
                              void* d_out, int out_size, void* d_ws, size_t ws_size,
                              hipStream_t stream) {
    const float* pred_prob  = (const float*)d_in[0];   // (B,C,N)
    const float* pred_mask  = (const float*)d_in[1];   // (B,N,24,24)
    const float* pred_mom   = (const float*)d_in[2];   // (B,N,4)
    const int*   tgt_class  = (const int*)  d_in[3];   // (B,M)
    const float* tgt_mask   = (const float*)d_in[4];   // (B,M,96,96)
    const float* tgt_mom    = (const float*)d_in[5];   // (B,M,4)
    float* out = (float*)d_out;

    // workspace carve-up (floats)
    float* ws    = (float*)d_ws;
    float* Q     = ws;                               // BB*NN*HW = 1,843,200
    float* D     = Q + (size_t)BB*NN*HW;             // 1,843,200
    float* sumP  = D + (size_t)BB*NN*HW;             // 200
    float* sumF0 = sumP + BB*NN;                     // 200
    float* tsum  = sumF0 + BB*NN;                    // 100
    float* pNeg  = tsum + BB*MM;                     // KCHUNKS*BB*NN*MM = 160,000
    float* pF    = pNeg + (size_t)KCHUNKS*BB*NN*MM;  // 160,000
    // total ~16.0 MB

    k_pre  <<<BB*NN + BB*MM, 256, 0, stream>>>(
        pred_mask, tgt_mask, Q, D, sumP, sumF0, tsum);
    k_dots <<<dim3(KCHUNKS, 8, BB), 256, 0, stream>>>(Q, D, tgt_mask, pNeg, pF);
    k_final<<<(BB*NN*MM + 255)/256, 256, 0, stream>>>(
        pNeg, pF, sumP, sumF0, tsum,
        pred_prob, pred_mom, tgt_class, tgt_mom, out);
}

// Round 8
// 99.855 us; speedup vs baseline: 1.0488x; 1.0488x over previous
//
#include <hip/hip_runtime.h>
#include <math.h>

#define BB 2
#define CC 10
#define NN 100
#define MM 50
#define HP 24
#define WP 24
#define HH 96
#define WW 96
#define HW (HH*WW)            // 9216
#define KCHUNKS 32
#define CHUNK (HW/KCHUNKS)    // 288
#define KC 32
#define NSTEPS (CHUNK/KC)     // 9
#define PAD 36                // 32 + 4 pad: b128 reads at worst 2-way bank aliasing (free)

static __device__ __forceinline__ float dot4(float4 a, float4 b) {
    return a.x*b.x + a.y*b.y + a.z*b.z + a.w*b.w;
}

// ---------------------------------------------------------------------------
// Kernel A (fused producer): blocks 0..199 do bilinear resize 24x24 -> 96x96
// (jax.image.resize: half-pixel centers, triangle kernel w/ edge renorm ==
// clamp) fused with per-pixel precompute
//   Q = 1 - 2p          (sum|p-t| = sumP + dot(Q,t)   for binary t, p in [0,1])
//   D = f1(p) - f0(p)   (sum focal = sumF0 + dot(D,t))
// and per-(b,n) reductions sumP, sumF0.
// Blocks 200..299 compute tsum[b,m] = sum(t) over HW (t binary => == sum|t|).
// ---------------------------------------------------------------------------
__global__ __launch_bounds__(256) void k_pre(
    const float* __restrict__ pm,         // (B,N,24,24)
    const float* __restrict__ tm,         // (B,M,96,96)
    float* __restrict__ Q, float* __restrict__ D,
    float* __restrict__ sumP, float* __restrict__ sumF0,
    float* __restrict__ tsum)
{
    const int tid = threadIdx.x;
    __shared__ float tile[HP*WP];
    __shared__ float red[8];

    if (blockIdx.x >= BB*NN) {
        // ---- tsum path ----
        const int bm = blockIdx.x - BB*NN;        // 0..BB*MM-1
        const float4* t4 = (const float4*)(tm + (size_t)bm * HW);
        float s = 0.f;
#pragma unroll
        for (int i = 0; i < 9; ++i) {             // 9216/4/256 = 9
            float4 v = t4[i*256 + tid];
            s += v.x + v.y + v.z + v.w;
        }
#pragma unroll
        for (int o = 32; o > 0; o >>= 1) s += __shfl_down(s, o);
        const int wid = tid >> 6, lane = tid & 63;
        if (lane == 0) red[wid] = s;
        __syncthreads();
        if (tid == 0) tsum[bm] = red[0] + red[1] + red[2] + red[3];
        return;
    }

    // ---- resize + Q/D path ----
    const int bn = blockIdx.x;                    // 0..BB*NN-1
    const float* in = pm + (size_t)bn * (HP*WP);
    for (int i = tid; i < HP*WP; i += 256) tile[i] = in[i];
    __syncthreads();

    float* q = Q + (size_t)bn * HW;
    float* d = D + (size_t)bn * HW;

    float sp = 0.f, sf = 0.f;
#pragma unroll 4
    for (int s = 0; s < HW/256; ++s) {
        const int idx = s*256 + tid;
        const int i = idx / WW;
        const int j = idx - i*WW;
        float y = (i + 0.5f)*0.25f - 0.5f;
        float x = (j + 0.5f)*0.25f - 0.5f;
        y = fminf(fmaxf(y, 0.f), 23.f);
        x = fminf(fmaxf(x, 0.f), 23.f);
        const int y0 = (int)y;
        const int x0 = (int)x;
        const float fy = y - (float)y0;
        const float fx = x - (float)x0;
        const int y1 = (y0 < HP-1) ? y0+1 : HP-1;
        const int x1 = (x0 < WP-1) ? x0+1 : WP-1;
        const float v00 = tile[y0*WP + x0], v01 = tile[y0*WP + x1];
        const float v10 = tile[y1*WP + x0], v11 = tile[y1*WP + x1];
        const float p = (1.f-fy)*((1.f-fx)*v00 + fx*v01)
                      +       fy*((1.f-fx)*v10 + fx*v11);

        const float pc  = fminf(fmaxf(p, 0.001f), 0.999f);
        const float omc = 1.f - pc;
        const float f1 = 0.25f * (-logf(pc))  * omc*omc;   // t==1 focal term
        const float f0 = 0.75f * (-logf(omc)) * pc*pc;     // t==0 focal term

        q[idx] = 1.f - 2.f*p;
        d[idx] = f1 - f0;
        sp += p;
        sf += f0;
    }

#pragma unroll
    for (int o = 32; o > 0; o >>= 1) {
        sp += __shfl_down(sp, o);
        sf += __shfl_down(sf, o);
    }
    const int wid = tid >> 6, lane = tid & 63;
    if (lane == 0) { red[wid] = sp; red[4+wid] = sf; }
    __syncthreads();
    if (tid == 0) {
        sumP[bn]  = red[0] + red[1] + red[2] + red[3];
        sumF0[bn] = red[4] + red[5] + red[6] + red[7];
    }
}

// ---------------------------------------------------------------------------
// Kernel B: the dual dot products
//   pNeg[kc,b,n,m] = dot(Q[b,n, chunk], T[b,m, chunk])
//   pF  [kc,b,n,m] = dot(D[b,n, chunk], T[b,m, chunk])
// Tiled 32n x 32m per block, 2x2 register blocking per thread, k split into
// 32 chunks of 288. grid = (32, 4*2, 2) = 512 blocks (2 blocks/CU, 2 w/SIMD),
// 256 threads. KC=32 -> LDS 3*32*36*4 = 13.8 KB.
// ---------------------------------------------------------------------------
__global__ __launch_bounds__(256) void k_dots(
    const float* __restrict__ Q, const float* __restrict__ D,
    const float* __restrict__ T,
    float* __restrict__ pNeg, float* __restrict__ pF)
{
    const int kc = blockIdx.x;               // 0..31
    const int nt = blockIdx.y >> 1;          // 0..3
    const int mt = blockIdx.y & 1;           // 0..1
    const int b  = blockIdx.z;               // 0..1
    const int tid = threadIdx.x;
    const int ni = tid >> 4;                 // 0..15
    const int mi = tid & 15;                 // 0..15

    __shared__ float tS[32][PAD];
    __shared__ float qS[32][PAD];
    __shared__ float dS[32][PAD];

    const int n0 = nt*32, m0 = mt*32;
    const int k0 = kc*CHUNK;

    // loader mapping: thread -> (row = tid>>3, one float4 at (tid&7)*4)
    const int lr = tid >> 3;                 // 0..31
    const int lc = (tid & 7) * 4;            // 0,4,..,28

    float accN[2][2] = {{0.f,0.f},{0.f,0.f}};
    float accF[2][2] = {{0.f,0.f},{0.f,0.f}};

    for (int s = 0; s < NSTEPS; ++s) {
        const int kb = k0 + s*KC;
        // ---- stage ----
        {
            const int n = n0 + lr;
            float4 qa = {0,0,0,0}, da = {0,0,0,0};
            if (n < NN) {
                qa = *(const float4*)(Q + ((size_t)b*NN + n)*HW + kb + lc);
                da = *(const float4*)(D + ((size_t)b*NN + n)*HW + kb + lc);
            }
            *(float4*)&qS[lr][lc] = qa;
            *(float4*)&dS[lr][lc] = da;

            const int m = m0 + lr;
            float4 ta = {0,0,0,0};
            if (m < MM) {
                ta = *(const float4*)(T + ((size_t)b*MM + m)*HW + kb + lc);
            }
            *(float4*)&tS[lr][lc] = ta;
        }
        __syncthreads();
        // ---- compute ----
#pragma unroll
        for (int kk = 0; kk < KC; kk += 4) {
            const float4 t0 = *(const float4*)&tS[mi   ][kk];
            const float4 t1 = *(const float4*)&tS[mi+16][kk];
            const float4 q0 = *(const float4*)&qS[ni   ][kk];
            const float4 q1 = *(const float4*)&qS[ni+16][kk];
            const float4 d0 = *(const float4*)&dS[ni   ][kk];
            const float4 d1 = *(const float4*)&dS[ni+16][kk];
            accN[0][0] += dot4(q0, t0);  accN[0][1] += dot4(q0, t1);
            accN[1][0] += dot4(q1, t0);  accN[1][1] += dot4(q1, t1);
            accF[0][0] += dot4(d0, t0);  accF[0][1] += dot4(d0, t1);
            accF[1][0] += dot4(d1, t0);  accF[1][1] += dot4(d1, t1);
        }
        __syncthreads();
    }

#pragma unroll
    for (int a = 0; a < 2; ++a)
#pragma unroll
        for (int c = 0; c < 2; ++c) {
            const int n = n0 + ni + a*16;
            const int m = m0 + mi + c*16;
            if (n < NN && m < MM) {
                const size_t o = (((size_t)kc*BB + b)*NN + n)*MM + m;
                pNeg[o] = accN[a][c];
                pF[o]   = accF[a][c];
            }
        }
}

// ---------------------------------------------------------------------------
// Kernel C: finalize — combine partials + dice/focal closed forms + class +
// momentum L1 / EIoU + class>0 mask. One thread per (b,n,m).
// ---------------------------------------------------------------------------
__global__ __launch_bounds__(256) void k_final(
    const float* __restrict__ pNeg, const float* __restrict__ pF,
    const float* __restrict__ sumP, const float* __restrict__ sumF0,
    const float* __restrict__ tsum,
    const float* __restrict__ prob,      // (B,C,N)
    const float* __restrict__ pmom,      // (B,N,4)
    const int*   __restrict__ tcls,      // (B,M)
    const float* __restrict__ tmom,      // (B,M,4)
    float* __restrict__ out)             // (B,N,M)
{
    const int idx = blockIdx.x*256 + threadIdx.x;
    if (idx >= BB*NN*MM) return;
    const int m = idx % MM;
    const int n = (idx / MM) % NN;
    const int b = idx / (NN*MM);

    const float PI_F     = 3.14159265358979323846f;
    const float TWO_PI_F = 6.28318530717958647692f;

    float nd = 0.f, fd = 0.f;
#pragma unroll
    for (int kc = 0; kc < KCHUNKS; ++kc) {
        const size_t o = (((size_t)kc*BB + b)*NN + n)*MM + m;
        nd += pNeg[o];
        fd += pF[o];
    }
    const float sp  = sumP[b*NN + n];
    const float sf0 = sumF0[b*NN + n];
    const float ts  = tsum[b*MM + m];

    const float neg = sp + nd;                    // sum |p - t|
    const float pos = sp + ts;                    // sum|p| + sum|t|
    const float cost_dice  = 1.f - (pos - neg) / (pos + 0.001f);
    const float cost_focal = (sf0 + fd) * (1.f / (float)HW);

    const int tc = tcls[b*MM + m];
    const float cost_class = -prob[((size_t)b*CC + tc)*NN + n];

    // calc_bbox(pred_momentum[b,n])
    const float* pr = pmom + ((size_t)b*NN + n)*4;
    const float p0 = expf(fminf(pr[0], 10.f));                       // pt
    const float p1 = TWO_PI_F / (1.f + expf(-pr[1]));                // rap
    const float p2 = TWO_PI_F / (1.f + expf(-pr[2]));                // phi
    const float p3 = expf(fminf(pr[3], 10.f));                       // m

    const float* tg = tmom + ((size_t)b*MM + m)*4;
    const float t0 = tg[0], t1 = tg[1], t2 = tg[2], t3 = tg[3];

    // ---- momentum L1 ----
    const float te2 = (p2 - t2 > PI_F) ? TWO_PI_F : 0.f;  // added to tgt phi
    const float pe2 = (t2 - p2 > PI_F) ? TWO_PI_F : 0.f;  // added to pred phi
    const float e0 = p0 / (t0 + 0.001f);
    const float e1 = p1 / (t1 + 0.001f);
    const float e2 = (p2 + pe2) / (t2 + te2 + 0.001f);
    const float e3 = p3 / (t3 + 0.001f);
    const float cost_l1 = 0.25f * (fabsf(e0 - 1.f) + fabsf(e1 - 1.f)
                                 + fabsf(e2 - 1.f) + fabsf(e3 - 1.f));

    // ---- EIoU ----  (w1,x1,y1,h1) = pred bbox, (w2,x2,y2,h2) = target
    const float w1 = p0, x1 = p1, y1o = p2, h1 = p3;
    const float w2 = t0, x2 = t1, y2o = t2, h2 = t3;
    const float y1 = y1o + ((y2o - y1o > PI_F) ? TWO_PI_F : 0.f);
    const float y2 = y2o + ((y1o - y2o > PI_F) ? TWO_PI_F : 0.f);

    const float xr1 = x1 + w1*0.5f, xl1 = x1 - w1*0.5f;
    const float xr2 = x2 + w2*0.5f, xl2 = x2 - w2*0.5f;
    const float yr1 = y1 + h1*0.5f, yl1 = y1 - h1*0.5f;
    const float yr2 = y2 + h2*0.5f, yl2 = y2 - h2*0.5f;

    const float wi = fminf(xr1, xr2) - fmaxf(xl1, xl2);
    const float hi = fminf(yr1, yr2) - fmaxf(yl1, yl2);
    const float iou = (wi > 0.f && hi > 0.f)
        ? wi*hi / (w1*h1 + w2*h2 - wi*hi + 0.001f) : 0.f;

    const float cw = fmaxf(xr1, xr2) - fminf(xl1, xl2);
    const float ch = fmaxf(yr1, yr2) - fminf(yl1, yl2);
    const float cw2 = cw*cw, ch2 = ch*ch;
    const float rho_w = (w1 - w2)*(w1 - w2) / (cw2 + 0.001f);
    const float rho_h = (h1 - h2)*(h1 - h2) / (ch2 + 0.001f);
    const float rho_d = ((x1 - x2)*(x1 - x2) + (y1 - y2)*(y1 - y2))
                        / (cw2 + ch2 + 0.001f);
    const float cost_eiou = 1.f - iou + rho_d + rho_w + rho_h;

    const float cost = 0.25f*cost_focal + 0.75f*cost_dice + cost_class
                     + 0.8f*cost_l1 + 0.2f*cost_eiou;
    out[idx] = (tc > 0) ? cost : 100000.0f;
}

// ---------------------------------------------------------------------------
extern "C" void kernel_launch(void* const* d_in, const int* in_sizes, int n_in,
                              void* d_out, int out_size, void* d_ws, size_t ws_size,
                              hipStream_t stream) {
    const float* pred_prob  = (const float*)d_in[0];   // (B,C,N)
    const float* pred_mask  = (const float*)d_in[1];   // (B,N,24,24)
    const float* pred_mom   = (const float*)d_in[2];   // (B,N,4)
    const int*   tgt_class  = (const int*)  d_in[3];   // (B,M)
    const float* tgt_mask   = (const float*)d_in[4];   // (B,M,96,96)
    const float* tgt_mom    = (const float*)d_in[5];   // (B,M,4)
    float* out = (float*)d_out;

    // workspace carve-up (floats)
    float* ws    = (float*)d_ws;
    float* Q     = ws;                               // BB*NN*HW = 1,843,200
    float* D     = Q + (size_t)BB*NN*HW;             // 1,843,200
    float* sumP  = D + (size_t)BB*NN*HW;             // 200
    float* sumF0 = sumP + BB*NN;                     // 200
    float* tsum  = sumF0 + BB*NN;                    // 100
    float* pNeg  = tsum + BB*MM;                     // KCHUNKS*BB*NN*MM = 320,000
    float* pF    = pNeg + (size_t)KCHUNKS*BB*NN*MM;  // 320,000
    // total ~17.3 MB

    k_pre  <<<BB*NN + BB*MM, 256, 0, stream>>>(
        pred_mask, tgt_mask, Q, D, sumP, sumF0, tsum);
    k_dots <<<dim3(KCHUNKS, 8, BB), 256, 0, stream>>>(Q, D, tgt_mask, pNeg, pF);
    k_final<<<(BB*NN*MM + 255)/256, 256, 0, stream>>>(
        pNeg, pF, sumP, sumF0, tsum,
        pred_prob, pred_mom, tgt_class, tgt_mom, out);
}

// Round 9
// 99.751 us; speedup vs baseline: 1.0499x; 1.0010x over previous
//
#include <hip/hip_runtime.h>
#include <math.h>

#define BB 2
#define CC 10
#define NN 100
#define MM 50
#define HP 24
#define WP 24
#define HH 96
#define WW 96
#define HW (HH*WW)            // 9216
#define KCHUNKS 32
#define CHUNK (HW/KCHUNKS)    // 288 = 3 output rows of 96
#define KC 32
#define NSTEPS (CHUNK/KC)     // 9
#define PAD 36                // 32 + 4 pad: b128 reads at worst 2-way bank aliasing (free)
#define PMPAD 76              // 3*24=72 + 4: n-stride 76 -> lr*12%32 distinct per lr in wave

static __device__ __forceinline__ float dot4(float4 a, float4 b) {
    return a.x*b.x + a.y*b.y + a.z*b.z + a.w*b.w;
}

// ---------------------------------------------------------------------------
// Kernel A (slim producer): blocks 0..199 compute ONLY the per-(b,n) sums
//   sumP  = sum p        (p = bilinear-resized pred mask, in [0,1])
//   sumF0 = sum f0(p)    (t==0 focal term)
// (no Q/D stores — k_dots recomputes those in-block). One log per pixel.
// Blocks 200..299 compute tsum[b,m] = sum(t) over HW (t binary == sum|t|).
// ---------------------------------------------------------------------------
__global__ __launch_bounds__(256) void k_pre(
    const float* __restrict__ pm,         // (B,N,24,24)
    const float* __restrict__ tm,         // (B,M,96,96)
    float* __restrict__ sumP, float* __restrict__ sumF0,
    float* __restrict__ tsum)
{
    const int tid = threadIdx.x;
    __shared__ float tile[HP*WP];
    __shared__ float red[8];

    if (blockIdx.x >= BB*NN) {
        // ---- tsum path ----
        const int bm = blockIdx.x - BB*NN;        // 0..BB*MM-1
        const float4* t4 = (const float4*)(tm + (size_t)bm * HW);
        float s = 0.f;
#pragma unroll
        for (int i = 0; i < 9; ++i) {             // 9216/4/256 = 9
            float4 v = t4[i*256 + tid];
            s += v.x + v.y + v.z + v.w;
        }
#pragma unroll
        for (int o = 32; o > 0; o >>= 1) s += __shfl_down(s, o);
        const int wid = tid >> 6, lane = tid & 63;
        if (lane == 0) red[wid] = s;
        __syncthreads();
        if (tid == 0) tsum[bm] = red[0] + red[1] + red[2] + red[3];
        return;
    }

    // ---- sums path ----
    const int bn = blockIdx.x;                    // 0..BB*NN-1
    const float* in = pm + (size_t)bn * (HP*WP);
    for (int i = tid; i < HP*WP; i += 256) tile[i] = in[i];
    __syncthreads();

    float sp = 0.f, sf = 0.f;
#pragma unroll 4
    for (int s = 0; s < HW/256; ++s) {
        const int idx = s*256 + tid;
        const int i = idx / WW;
        const int j = idx - i*WW;
        float y = (i + 0.5f)*0.25f - 0.5f;
        float x = (j + 0.5f)*0.25f - 0.5f;
        y = fminf(fmaxf(y, 0.f), 23.f);
        x = fminf(fmaxf(x, 0.f), 23.f);
        const int y0 = (int)y;
        const int x0 = (int)x;
        const float fy = y - (float)y0;
        const float fx = x - (float)x0;
        const int y1 = (y0 < HP-1) ? y0+1 : HP-1;
        const int x1 = (x0 < WP-1) ? x0+1 : WP-1;
        const float v00 = tile[y0*WP + x0], v01 = tile[y0*WP + x1];
        const float v10 = tile[y1*WP + x0], v11 = tile[y1*WP + x1];
        const float p = (1.f-fy)*((1.f-fx)*v00 + fx*v01)
                      +       fy*((1.f-fx)*v10 + fx*v11);

        const float pc  = fminf(fmaxf(p, 0.001f), 0.999f);
        const float omc = 1.f - pc;
        sp += p;
        sf += 0.75f * (-logf(omc)) * pc*pc;       // f0 (t==0 focal term)
    }

#pragma unroll
    for (int o = 32; o > 0; o >>= 1) {
        sp += __shfl_down(sp, o);
        sf += __shfl_down(sf, o);
    }
    const int wid = tid >> 6, lane = tid & 63;
    if (lane == 0) { red[wid] = sp; red[4+wid] = sf; }
    __syncthreads();
    if (tid == 0) {
        sumP[bn]  = red[0] + red[1] + red[2] + red[3];
        sumF0[bn] = red[4] + red[5] + red[6] + red[7];
    }
}

// ---------------------------------------------------------------------------
// Kernel B (fused): dual dot products with IN-BLOCK resize recompute.
//   pNeg[kc,b,n,m] = dot(Q[b,n,chunk], T[b,m,chunk]),  Q = 1-2p
//   pF  [kc,b,n,m] = dot(D[b,n,chunk], T[b,m,chunk]),  D = f1-f0
// Q/D are generated into LDS from the 24x24 pred masks (never touch global):
// a k-chunk of 288 px = output rows i0..i0+2; y-span 0.5 => input rows
// r0..r0+2 suffice (r0 = floor(clamp(y(i0)))). Stage 32n x 3rows x 24cols.
// grid = (32, 8, 2) = 512 blocks, 256 thr, LDS 9.7+13.8 = 23.5 KB.
// ---------------------------------------------------------------------------
__global__ __launch_bounds__(256) void k_dots(
    const float* __restrict__ pm,        // (B,N,24,24)
    const float* __restrict__ T,         // (B,M,96,96)
    float* __restrict__ pNeg, float* __restrict__ pF)
{
    const int kc = blockIdx.x;               // 0..31
    const int nt = blockIdx.y >> 1;          // 0..3
    const int mt = blockIdx.y & 1;           // 0..1
    const int b  = blockIdx.z;               // 0..1
    const int tid = threadIdx.x;
    const int ni = tid >> 4;                 // 0..15
    const int mi = tid & 15;                 // 0..15

    __shared__ float pmS[32][PMPAD];         // 3 input rows x 24 per n
    __shared__ float tS[32][PAD];
    __shared__ float qS[32][PAD];
    __shared__ float dS[32][PAD];

    const int n0 = nt*32, m0 = mt*32;
    const int k0 = kc*CHUNK;
    const int i0 = 3*kc;                     // first output row of this chunk

    // input-row window for this chunk
    const float ymin = fminf(fmaxf(((float)i0 + 0.5f)*0.25f - 0.5f, 0.f), 23.f);
    const int r0 = (int)ymin;                // rows r0..r0+2 cover the chunk

    // ---- stage pred-mask rows: 32 n x 3 rows x 6 float4 = 576 quads ----
#pragma unroll
    for (int it = 0; it < 3; ++it) {
        const int q = it*256 + tid;
        if (q < 32*3*6) {
            const int n   = q / 18;          // 18 quads per n
            const int rem = q - n*18;
            const int r   = rem / 6;
            const int c4  = rem - r*6;
            const int gn  = n0 + n;
            float4 v = {0,0,0,0};
            if (gn < NN) {
                const int row = (r0 + r < HP-1) ? r0 + r : HP-1;
                v = *(const float4*)(pm + ((size_t)b*NN + gn)*(HP*WP)
                                        + row*WP + c4*4);
            }
            *(float4*)&pmS[n][r*WP + c4*4] = v;
        }
    }

    // loader mapping: thread -> (row lr = tid>>3, 4 elements at (tid&7)*4)
    const int lr = tid >> 3;                 // 0..31
    const int lc = (tid & 7) * 4;            // 0,4,..,28

    float accN[2][2] = {{0.f,0.f},{0.f,0.f}};
    float accF[2][2] = {{0.f,0.f},{0.f,0.f}};

    for (int s = 0; s < NSTEPS; ++s) {
        const int kb = k0 + s*KC;
        __syncthreads();                     // pmS ready (1st iter) / prev compute done
        // ---- stage T tile + generate Q/D tiles from pmS ----
        {
            const int m = m0 + lr;
            float4 ta = {0,0,0,0};
            if (m < MM) {
                ta = *(const float4*)(T + ((size_t)b*MM + m)*HW + kb + lc);
            }
            *(float4*)&tS[lr][lc] = ta;

#pragma unroll
            for (int u = 0; u < 4; ++u) {
                const int ke = s*KC + lc + u;        // 0..287 within chunk
                const int di = ke / WW;              // 0..2
                const int j  = ke - di*WW;
                const int i  = i0 + di;
                float y = ((float)i + 0.5f)*0.25f - 0.5f;
                float x = ((float)j + 0.5f)*0.25f - 0.5f;
                y = fminf(fmaxf(y, 0.f), 23.f);
                x = fminf(fmaxf(x, 0.f), 23.f);
                const int y0 = (int)y;
                const int x0 = (int)x;
                const float fy = y - (float)y0;
                const float fx = x - (float)x0;
                const int yi0 = y0 - r0;                       // 0..2
                const int yi1 = ((y0 < HP-1) ? y0+1 : HP-1) - r0;
                const int x1  = (x0 < WP-1) ? x0+1 : WP-1;
                const float v00 = pmS[lr][yi0*WP + x0], v01 = pmS[lr][yi0*WP + x1];
                const float v10 = pmS[lr][yi1*WP + x0], v11 = pmS[lr][yi1*WP + x1];
                const float p = (1.f-fy)*((1.f-fx)*v00 + fx*v01)
                              +       fy*((1.f-fx)*v10 + fx*v11);
                const float pc  = fminf(fmaxf(p, 0.001f), 0.999f);
                const float omc = 1.f - pc;
                const float f1 = 0.25f * (-logf(pc))  * omc*omc;
                const float f0 = 0.75f * (-logf(omc)) * pc*pc;
                qS[lr][lc+u] = 1.f - 2.f*p;
                dS[lr][lc+u] = f1 - f0;
            }
        }
        __syncthreads();
        // ---- compute ----
#pragma unroll
        for (int kk = 0; kk < KC; kk += 4) {
            const float4 t0 = *(const float4*)&tS[mi   ][kk];
            const float4 t1 = *(const float4*)&tS[mi+16][kk];
            const float4 q0 = *(const float4*)&qS[ni   ][kk];
            const float4 q1 = *(const float4*)&qS[ni+16][kk];
            const float4 d0 = *(const float4*)&dS[ni   ][kk];
            const float4 d1 = *(const float4*)&dS[ni+16][kk];
            accN[0][0] += dot4(q0, t0);  accN[0][1] += dot4(q0, t1);
            accN[1][0] += dot4(q1, t0);  accN[1][1] += dot4(q1, t1);
            accF[0][0] += dot4(d0, t0);  accF[0][1] += dot4(d0, t1);
            accF[1][0] += dot4(d1, t0);  accF[1][1] += dot4(d1, t1);
        }
    }

#pragma unroll
    for (int a = 0; a < 2; ++a)
#pragma unroll
        for (int c = 0; c < 2; ++c) {
            const int n = n0 + ni + a*16;
            const int m = m0 + mi + c*16;
            if (n < NN && m < MM) {
                const size_t o = (((size_t)kc*BB + b)*NN + n)*MM + m;
                pNeg[o] = accN[a][c];
                pF[o]   = accF[a][c];
            }
        }
}

// ---------------------------------------------------------------------------
// Kernel C: finalize — combine partials + dice/focal closed forms + class +
// momentum L1 / EIoU + class>0 mask. One thread per (b,n,m).
// ---------------------------------------------------------------------------
__global__ __launch_bounds__(256) void k_final(
    const float* __restrict__ pNeg, const float* __restrict__ pF,
    const float* __restrict__ sumP, const float* __restrict__ sumF0,
    const float* __restrict__ tsum,
    const float* __restrict__ prob,      // (B,C,N)
    const float* __restrict__ pmom,      // (B,N,4)
    const int*   __restrict__ tcls,      // (B,M)
    const float* __restrict__ tmom,      // (B,M,4)
    float* __restrict__ out)             // (B,N,M)
{
    const int idx = blockIdx.x*256 + threadIdx.x;
    if (idx >= BB*NN*MM) return;
    const int m = idx % MM;
    const int n = (idx / MM) % NN;
    const int b = idx / (NN*MM);

    const float PI_F     = 3.14159265358979323846f;
    const float TWO_PI_F = 6.28318530717958647692f;

    float nd = 0.f, fd = 0.f;
#pragma unroll
    for (int kc = 0; kc < KCHUNKS; ++kc) {
        const size_t o = (((size_t)kc*BB + b)*NN + n)*MM + m;
        nd += pNeg[o];
        fd += pF[o];
    }
    const float sp  = sumP[b*NN + n];
    const float sf0 = sumF0[b*NN + n];
    const float ts  = tsum[b*MM + m];

    const float neg = sp + nd;                    // sum |p - t|
    const float pos = sp + ts;                    // sum|p| + sum|t|
    const float cost_dice  = 1.f - (pos - neg) / (pos + 0.001f);
    const float cost_focal = (sf0 + fd) * (1.f / (float)HW);

    const int tc = tcls[b*MM + m];
    const float cost_class = -prob[((size_t)b*CC + tc)*NN + n];

    // calc_bbox(pred_momentum[b,n])
    const float* pr = pmom + ((size_t)b*NN + n)*4;
    const float p0 = expf(fminf(pr[0], 10.f));                       // pt
    const float p1 = TWO_PI_F / (1.f + expf(-pr[1]));                // rap
    const float p2 = TWO_PI_F / (1.f + expf(-pr[2]));                // phi
    const float p3 = expf(fminf(pr[3], 10.f));                       // m

    const float* tg = tmom + ((size_t)b*MM + m)*4;
    const float t0 = tg[0], t1 = tg[1], t2 = tg[2], t3 = tg[3];

    // ---- momentum L1 ----
    const float te2 = (p2 - t2 > PI_F) ? TWO_PI_F : 0.f;  // added to tgt phi
    const float pe2 = (t2 - p2 > PI_F) ? TWO_PI_F : 0.f;  // added to pred phi
    const float e0 = p0 / (t0 + 0.001f);
    const float e1 = p1 / (t1 + 0.001f);
    const float e2 = (p2 + pe2) / (t2 + te2 + 0.001f);
    const float e3 = p3 / (t3 + 0.001f);
    const float cost_l1 = 0.25f * (fabsf(e0 - 1.f) + fabsf(e1 - 1.f)
                                 + fabsf(e2 - 1.f) + fabsf(e3 - 1.f));

    // ---- EIoU ----  (w1,x1,y1,h1) = pred bbox, (w2,x2,y2,h2) = target
    const float w1 = p0, x1 = p1, y1o = p2, h1 = p3;
    const float w2 = t0, x2 = t1, y2o = t2, h2 = t3;
    const float y1 = y1o + ((y2o - y1o > PI_F) ? TWO_PI_F : 0.f);
    const float y2 = y2o + ((y1o - y2o > PI_F) ? TWO_PI_F : 0.f);

    const float xr1 = x1 + w1*0.5f, xl1 = x1 - w1*0.5f;
    const float xr2 = x2 + w2*0.5f, xl2 = x2 - w2*0.5f;
    const float yr1 = y1 + h1*0.5f, yl1 = y1 - h1*0.5f;
    const float yr2 = y2 + h2*0.5f, yl2 = y2 - h2*0.5f;

    const float wi = fminf(xr1, xr2) - fmaxf(xl1, xl2);
    const float hi = fminf(yr1, yr2) - fmaxf(yl1, yl2);
    const float iou = (wi > 0.f && hi > 0.f)
        ? wi*hi / (w1*h1 + w2*h2 - wi*hi + 0.001f) : 0.f;

    const float cw = fmaxf(xr1, xr2) - fminf(xl1, xl2);
    const float ch = fmaxf(yr1, yr2) - fminf(yl1, yl2);
    const float cw2 = cw*cw, ch2 = ch*ch;
    const float rho_w = (w1 - w2)*(w1 - w2) / (cw2 + 0.001f);
    const float rho_h = (h1 - h2)*(h1 - h2) / (ch2 + 0.001f);
    const float rho_d = ((x1 - x2)*(x1 - x2) + (y1 - y2)*(y1 - y2))
                        / (cw2 + ch2 + 0.001f);
    const float cost_eiou = 1.f - iou + rho_d + rho_w + rho_h;

    const float cost = 0.25f*cost_focal + 0.75f*cost_dice + cost_class
                     + 0.8f*cost_l1 + 0.2f*cost_eiou;
    out[idx] = (tc > 0) ? cost : 100000.0f;
}

// ---------------------------------------------------------------------------
extern "C" void kernel_launch(void* const* d_in, const int* in_sizes, int n_in,
                              void* d_out, int out_size, void* d_ws, size_t ws_size,
                              hipStream_t stream) {
    const float* pred_prob  = (const float*)d_in[0];   // (B,C,N)
    const float* pred_mask  = (const float*)d_in[1];   // (B,N,24,24)
    const float* pred_mom   = (const float*)d_in[2];   // (B,N,4)
    const int*   tgt_class  = (const int*)  d_in[3];   // (B,M)
    const float* tgt_mask   = (const float*)d_in[4];   // (B,M,96,96)
    const float* tgt_mom    = (const float*)d_in[5];   // (B,M,4)
    float* out = (float*)d_out;

    // workspace carve-up (floats) — Q/D eliminated, ~2.6 MB total
    float* ws    = (float*)d_ws;
    float* sumP  = ws;                               // 200
    float* sumF0 = sumP + BB*NN;                     // 200
    float* tsum  = sumF0 + BB*NN;                    // 100
    float* pNeg  = tsum + BB*MM;                     // KCHUNKS*BB*NN*MM = 320,000
    float* pF    = pNeg + (size_t)KCHUNKS*BB*NN*MM;  // 320,000

    k_pre  <<<BB*NN + BB*MM, 256, 0, stream>>>(
        pred_mask, tgt_mask, sumP, sumF0, tsum);
    k_dots <<<dim3(KCHUNKS, 8, BB), 256, 0, stream>>>(
        pred_mask, tgt_mask, pNeg, pF);
    k_final<<<(BB*NN*MM + 255)/256, 256, 0, stream>>>(
        pNeg, pF, sumP, sumF0, tsum,
        pred_prob, pred_mom, tgt_class, tgt_mom, out);
}